// Round 2
// baseline (149.882 us; speedup 1.0000x reference)
//
#include <hip/hip_runtime.h>

// ---- types ----
typedef __bf16 bf8_t  __attribute__((ext_vector_type(8)));   // 8 x bf16 = 4 VGPR (MFMA A/B frag)
typedef float  f4_t   __attribute__((ext_vector_type(4)));   // MFMA C/D frag
typedef unsigned short us4_t __attribute__((ext_vector_type(4)));

#define N_ROWS 4096
#define D_K    1024
#define TEMP_INV 20.0f   // 1 / 0.05  (folded into x-normalization)

// fp32 -> bf16, round-to-nearest-even (no NaN in this problem)
__device__ __forceinline__ unsigned short f2bf(float f) {
    unsigned int u = __builtin_bit_cast(unsigned int, f);
    u += 0x7fffu + ((u >> 16) & 1u);
    return (unsigned short)(u >> 16);
}

// async global->LDS, 16B per lane. LDS dest must be wave-uniform base + lane*16.
__device__ __forceinline__ void gl_lds16(const __bf16* g, __bf16* l) {
    __builtin_amdgcn_global_load_lds(
        (const __attribute__((address_space(1))) unsigned int*)g,
        (__attribute__((address_space(3))) unsigned int*)l,
        16, 0, 0);
}

// ---------------- fused row normalize for both inputs: v / max(||v||, eps), fp32 -> bf16 ----
// (unchanged, verified; ~7.6 us, at memory roofline for 48 MB)
__global__ __launch_bounds__(256) void norm_rows_kernel(
    const float* __restrict__ x, const float* __restrict__ y,
    unsigned short* __restrict__ xb, unsigned short* __restrict__ yb)
{
    const int b   = blockIdx.x;
    const int row = b & (N_ROWS - 1);
    const bool isx = (b < N_ROWS);
    const float* in     = isx ? x  : y;
    unsigned short* out = isx ? xb : yb;
    const float post    = isx ? TEMP_INV : 1.0f;
    const int t = threadIdx.x;
    const float4* ip = (const float4*)(in + (size_t)row * D_K);
    float4 v = ip[t];
    float ss = v.x*v.x + v.y*v.y + v.z*v.z + v.w*v.w;
    #pragma unroll
    for (int off = 32; off > 0; off >>= 1)
        ss += __shfl_down(ss, off, 64);
    __shared__ float red[4];
    if ((t & 63) == 0) red[t >> 6] = ss;
    __syncthreads();
    float tot   = red[0] + red[1] + red[2] + red[3];
    float scale = post / fmaxf(sqrtf(tot), 1e-8f);
    us4_t o;
    o.x = f2bf(v.x * scale);
    o.y = f2bf(v.y * scale);
    o.z = f2bf(v.z * scale);
    o.w = f2bf(v.w * scale);
    *(us4_t*)(out + (size_t)row * D_K + t * 4) = o;
}

// ---------------- C = A . B^T  ----------------------------------------------------------
// 256x256 tile, BK=64, 512 threads = 8 waves (2 M-halves x 4 N-quarters), per-wave 128x64 C.
// 4 phases per K-tile, counted vmcnt, raw s_barrier, setprio around MFMA clusters.
// LDS 128 KiB (A,B double-buffered).  KERNEL BODY IDENTICAL TO R1 (clean A/B on launch).
//
// R1 post-mortem: per-block lifetime 45.52/2 = 22.76 us == m201 prediction (22.0 us);
// MfmaUtil 27% ~ 62%/2, Occupancy 16% ~ 25%/2 -> the 2x is CU load imbalance from the
// fragile exactly-1-block-per-CU dispatch (one doubled CU serializes the whole grid),
// NOT schedule inefficiency. Fix: cooperative launch forces all-256-resident = 1:1.
//
// STAGER == READER partition (makes per-wave in-order vmcnt a sufficient completion proof):
//   A rows [wm*128+qm*64, +64)   staged by the 4 waves with that wm  (2 loads/thread)
//   B rows [wn*64 +qn*32, +32)   staged by the 2 waves with that wn  (2 loads/thread)
// Per-tile issue counts per wave: p1: A(q0)+B(q0)=4, p2: B(q1)=2, p3: A(q1)=2, p4: 0.
// Snake quadrant order p1..p4 = (q00, q01, q11, q10) so frag regs are reused between phases.
//
// vmcnt ledger (steady state, 8 outstanding max; drain target = data consumed next phase):
//   end p1: vmcnt(6) -> drains prev-tile-p2's B(q1) of CURRENT tile  (read in p2)
//   end p2: vmcnt(6) -> drains prev-tile-p3's A(q1) of CURRENT tile  (read in p3)
//   end p3: none     (p4 reads B(q0), staged 7 phases ago, long drained)
//   end p4: vmcnt(4) -> drains this-tile-p1's A(q0)+B(q0) of NEXT tile (read in next p1)
// Prologue: full tile-0 stage + vmcnt(0); first-iteration waits are no-ops by count.
// Epilogue tile: vmcnt(2) after p1, vmcnt(0) after p2, no stages.
//
// LDS swizzle: slot (row, g) holds global 8-elem k-group g ^ (row&7); applied on the GLOBAL
// source address during staging. Fragment read start group = (quad + 4*kk) ^ (l15&7) ->
// measured ZERO SQ_LDS_BANK_CONFLICT (R1). Do not switch to 32x32 MFMA (R3 of prior
// session: conflicts + -8%).
__global__ __launch_bounds__(512, 2) void cosim_gemm256_kernel(
    const unsigned short* __restrict__ Aus,
    const unsigned short* __restrict__ Bus,
    float* __restrict__ C)
{
    const __bf16* A = (const __bf16*)Aus;
    const __bf16* B = (const __bf16*)Bus;

    __shared__ __align__(16) __bf16 As[2][256 * 64];   // 64 KB
    __shared__ __align__(16) __bf16 Bs[2][256 * 64];   // 64 KB

    const int t    = threadIdx.x;
    const int lane = t & 63;
    const int wid  = t >> 6;       // 0..7
    const int wm   = wid >> 2;     // 0..1   M half
    const int wn   = wid & 3;      // 0..3   N quarter
    const int bm   = blockIdx.x;
    const int bn   = blockIdx.y;
    const int l15  = lane & 15;
    const int quad = lane >> 4;

    // ---- staging constants (see partition above) ----
    const int slA0 = wn * 64 + lane;          // 0..255
    const int slA1 = slA0 + 256;
    const int rA0 = slA0 >> 3, rA1 = slA1 >> 3;
    const int gA0 = (slA0 & 7) ^ (rA0 & 7);   // swizzled global k-group
    const int gA1 = (slA1 & 7) ^ (rA1 & 7);
    const size_t gaOff0 = (size_t)(bm * 256 + wm * 128 + rA0) * D_K + gA0 * 8;
    const size_t gaOff1 = (size_t)(bm * 256 + wm * 128 + rA1) * D_K + gA1 * 8;
    const int laOff0 = wm * 8192 + slA0 * 8;  // elems; + qm*4096
    const int laOff1 = wm * 8192 + slA1 * 8;
    const int slB0 = wm * 64 + lane;          // 0..127
    const int slB1 = slB0 + 128;
    const int rB0 = slB0 >> 3, rB1 = slB1 >> 3;
    const int gB0 = (slB0 & 7) ^ (rB0 & 7);
    const int gB1 = (slB1 & 7) ^ (rB1 & 7);
    const size_t gbOff0 = (size_t)(bn * 256 + wn * 64 + rB0) * D_K + gB0 * 8;
    const size_t gbOff1 = (size_t)(bn * 256 + wn * 64 + rB1) * D_K + gB1 * 8;
    const int lbOff0 = wn * 4096 + slB0 * 8;  // elems; + qn*2048
    const int lbOff1 = wn * 4096 + slB1 * 8;

#define STAGE_A(buf, qm, kelem) do { \
    gl_lds16(A + gaOff0 + (qm) * 65536 + (kelem), &As[buf][laOff0 + (qm) * 4096]); \
    gl_lds16(A + gaOff1 + (qm) * 65536 + (kelem), &As[buf][laOff1 + (qm) * 4096]); } while (0)
#define STAGE_B(buf, qn, kelem) do { \
    gl_lds16(B + gbOff0 + (qn) * 32768 + (kelem), &Bs[buf][lbOff0 + (qn) * 2048]); \
    gl_lds16(B + gbOff1 + (qn) * 32768 + (kelem), &Bs[buf][lbOff1 + (qn) * 2048]); } while (0)

    // ---- fragment read constants ----
    const int g0 = quad ^ (l15 & 7);          // kk=0 swizzled group
    const int g1 = (quad + 4) ^ (l15 & 7);    // kk=1
    const int aRd = (wm * 128 + l15) * 64;    // + qm*4096 + mi*1024 + g*8
    const int bRd = (wn * 64 + l15) * 64;     // + qn*2048 + ni*1024 + g*8

#define LDA(qm, mi, kk) (*(const bf8_t*)(&As[cur][aRd + (qm) * 4096 + (mi) * 1024 + ((kk) ? g1 : g0) * 8]))
#define LDB(qn, ni, kk) (*(const bf8_t*)(&Bs[cur][bRd + (qn) * 2048 + (ni) * 1024 + ((kk) ? g1 : g0) * 8]))

    f4_t acc[8][4];
    #pragma unroll
    for (int mi = 0; mi < 8; mi++)
        #pragma unroll
        for (int ni = 0; ni < 4; ni++) {
            acc[mi][ni][0] = 0.f; acc[mi][ni][1] = 0.f;
            acc[mi][ni][2] = 0.f; acc[mi][ni][3] = 0.f;
        }

    bf8_t af[4][2];   // A frags of current qm (4 mi x 2 kk)
    bf8_t bf[2][2];   // B frags of current qn (2 ni x 2 kk)

#define MFMA_QUAD(QM, QN) do { \
    __builtin_amdgcn_s_setprio(1); \
    _Pragma("unroll") \
    for (int mi = 0; mi < 4; mi++) \
        _Pragma("unroll") \
        for (int ni = 0; ni < 2; ni++) { \
            acc[(QM)*4+mi][(QN)*2+ni] = __builtin_amdgcn_mfma_f32_16x16x32_bf16( \
                af[mi][0], bf[ni][0], acc[(QM)*4+mi][(QN)*2+ni], 0, 0, 0); \
            acc[(QM)*4+mi][(QN)*2+ni] = __builtin_amdgcn_mfma_f32_16x16x32_bf16( \
                af[mi][1], bf[ni][1], acc[(QM)*4+mi][(QN)*2+ni], 0, 0, 0); \
        } \
    __builtin_amdgcn_s_setprio(0); } while (0)

#define FENCE_LGKM() do { \
    asm volatile("s_waitcnt lgkmcnt(0)"); \
    __builtin_amdgcn_sched_barrier(0); } while (0)

    // ---- prologue: full tile 0 into buf 0 ----
    STAGE_A(0, 0, 0); STAGE_B(0, 0, 0);
    STAGE_B(0, 1, 0); STAGE_A(0, 1, 0);
    asm volatile("s_waitcnt vmcnt(0)");
    __builtin_amdgcn_s_barrier();

    // ---- main loop: compute tile tt from buf cur, stage tile tt+1 into nxt ----
    for (int tt = 0; tt < 15; ++tt) {
        const int cur = tt & 1;
        const int nxt = cur ^ 1;
        const int k1  = (tt + 1) * 64;

        // phase 1: quadrant (0,0) — 12 ds_reads, stage A(q0)+B(q0) of next tile
        #pragma unroll
        for (int mi = 0; mi < 4; mi++) { af[mi][0] = LDA(0, mi, 0); af[mi][1] = LDA(0, mi, 1); }
        #pragma unroll
        for (int ni = 0; ni < 2; ni++) { bf[ni][0] = LDB(0, ni, 0); bf[ni][1] = LDB(0, ni, 1); }
        STAGE_A(nxt, 0, k1); STAGE_B(nxt, 0, k1);
        __builtin_amdgcn_s_barrier();
        FENCE_LGKM();
        MFMA_QUAD(0, 0);
        asm volatile("s_waitcnt vmcnt(6)");
        __builtin_amdgcn_s_barrier();

        // phase 2: quadrant (0,1) — reuse af, read B(q1), stage B(q1) of next tile
        #pragma unroll
        for (int ni = 0; ni < 2; ni++) { bf[ni][0] = LDB(1, ni, 0); bf[ni][1] = LDB(1, ni, 1); }
        STAGE_B(nxt, 1, k1);
        __builtin_amdgcn_s_barrier();
        FENCE_LGKM();
        MFMA_QUAD(0, 1);
        asm volatile("s_waitcnt vmcnt(6)");
        __builtin_amdgcn_s_barrier();

        // phase 3: quadrant (1,1) — reuse bf, read A(q1), stage A(q1) of next tile
        #pragma unroll
        for (int mi = 0; mi < 4; mi++) { af[mi][0] = LDA(1, mi, 0); af[mi][1] = LDA(1, mi, 1); }
        STAGE_A(nxt, 1, k1);
        __builtin_amdgcn_s_barrier();
        FENCE_LGKM();
        MFMA_QUAD(1, 1);
        __builtin_amdgcn_s_barrier();                 // no vmcnt: p4's data drained long ago

        // phase 4: quadrant (1,0) — reuse af, re-read B(q0); no stage
        #pragma unroll
        for (int ni = 0; ni < 2; ni++) { bf[ni][0] = LDB(0, ni, 0); bf[ni][1] = LDB(0, ni, 1); }
        __builtin_amdgcn_s_barrier();
        FENCE_LGKM();
        MFMA_QUAD(1, 0);
        asm volatile("s_waitcnt vmcnt(4)");
        __builtin_amdgcn_s_barrier();
    }

    // ---- epilogue: tile 15 in buf 1; leftover in-flight: B(q1) (oldest 2), A(q1) ----
    {
        const int cur = 1;
        // phase 1
        #pragma unroll
        for (int mi = 0; mi < 4; mi++) { af[mi][0] = LDA(0, mi, 0); af[mi][1] = LDA(0, mi, 1); }
        #pragma unroll
        for (int ni = 0; ni < 2; ni++) { bf[ni][0] = LDB(0, ni, 0); bf[ni][1] = LDB(0, ni, 1); }
        __builtin_amdgcn_s_barrier();
        FENCE_LGKM();
        MFMA_QUAD(0, 0);
        asm volatile("s_waitcnt vmcnt(2)");           // drains B(q1) of tile 15
        __builtin_amdgcn_s_barrier();
        // phase 2
        #pragma unroll
        for (int ni = 0; ni < 2; ni++) { bf[ni][0] = LDB(1, ni, 0); bf[ni][1] = LDB(1, ni, 1); }
        __builtin_amdgcn_s_barrier();
        FENCE_LGKM();
        MFMA_QUAD(0, 1);
        asm volatile("s_waitcnt vmcnt(0)");           // drains A(q1) of tile 15
        __builtin_amdgcn_s_barrier();
        // phase 3
        #pragma unroll
        for (int mi = 0; mi < 4; mi++) { af[mi][0] = LDA(1, mi, 0); af[mi][1] = LDA(1, mi, 1); }
        __builtin_amdgcn_s_barrier();
        FENCE_LGKM();
        MFMA_QUAD(1, 1);
        __builtin_amdgcn_s_barrier();
        // phase 4
        #pragma unroll
        for (int ni = 0; ni < 2; ni++) { bf[ni][0] = LDB(0, ni, 0); bf[ni][1] = LDB(0, ni, 1); }
        FENCE_LGKM();
        MFMA_QUAD(1, 0);
    }

    // ---- C write: C/D layout col = lane&15, row = (lane>>4)*4 + reg [m89/m91 verified] ----
    #pragma unroll
    for (int mi = 0; mi < 8; mi++) {
        const int row = bm * 256 + wm * 128 + mi * 16 + quad * 4;
        #pragma unroll
        for (int ni = 0; ni < 4; ni++) {
            const int col = bn * 256 + wn * 64 + ni * 16 + l15;
            #pragma unroll
            for (int r = 0; r < 4; r++)
                C[(size_t)(row + r) * N_ROWS + col] = acc[mi][ni][r];
        }
    }

#undef STAGE_A
#undef STAGE_B
#undef LDA
#undef LDB
#undef MFMA_QUAD
#undef FENCE_LGKM
}

extern "C" void kernel_launch(void* const* d_in, const int* in_sizes, int n_in,
                              void* d_out, int out_size, void* d_ws, size_t ws_size,
                              hipStream_t stream)
{
    const float* x = (const float*)d_in[0];
    const float* y = (const float*)d_in[1];
    float* out = (float*)d_out;

    unsigned short* xb = (unsigned short*)d_ws;                 // 8 MB
    unsigned short* yb = xb + (size_t)N_ROWS * D_K;             // 8 MB

    norm_rows_kernel<<<2 * N_ROWS, 256, 0, stream>>>(x, y, xb, yb);

    // Cooperative launch: forces all 256 blocks co-resident -> exactly 1 block/CU,
    // eliminating the doubled-CU serialization diagnosed in R1 (2x wall time).
    dim3 grid(N_ROWS / 256, N_ROWS / 256);                      // 16x16 = 256 blocks
    dim3 blk(512);
    const unsigned short* aArg = xb;
    const unsigned short* bArg = yb;
    float* cArg = out;
    void* args[] = {(void*)&aArg, (void*)&bArg, (void*)&cArg};
    hipError_t e = hipLaunchCooperativeKernel((const void*)cosim_gemm256_kernel,
                                              grid, blk, args, 0, stream);
    if (e != hipSuccess) {
        // fallback: plain launch (R1 behavior) so the bench still completes
        cosim_gemm256_kernel<<<grid, blk, 0, stream>>>(xb, yb, out);
    }
}

// Round 3
// 123.571 us; speedup vs baseline: 1.2129x; 1.2129x over previous
//
#include <hip/hip_runtime.h>

// ---- types ----
typedef __bf16 bf8_t  __attribute__((ext_vector_type(8)));   // 8 x bf16 = 4 VGPR (MFMA A/B frag)
typedef float  f4_t   __attribute__((ext_vector_type(4)));   // MFMA C/D frag
typedef unsigned short us4_t __attribute__((ext_vector_type(4)));

#define N_ROWS 4096
#define D_K    1024
#define TEMP_INV 20.0f   // 1 / 0.05  (folded into x-normalization)

// fp32 -> bf16, round-to-nearest-even (no NaN in this problem)
__device__ __forceinline__ unsigned short f2bf(float f) {
    unsigned int u = __builtin_bit_cast(unsigned int, f);
    u += 0x7fffu + ((u >> 16) & 1u);
    return (unsigned short)(u >> 16);
}

// async global->LDS, 16B per lane. LDS dest must be wave-uniform base + lane*16.
__device__ __forceinline__ void gl_lds16(const __bf16* g, __bf16* l) {
    __builtin_amdgcn_global_load_lds(
        (const __attribute__((address_space(1))) unsigned int*)g,
        (__attribute__((address_space(3))) unsigned int*)l,
        16, 0, 0);
}

// ---------------- fused row normalize for both inputs: v / max(||v||, eps), fp32 -> bf16 ----
// (unchanged, verified; ~7.6 us, at memory roofline for 48 MB)
__global__ __launch_bounds__(256) void norm_rows_kernel(
    const float* __restrict__ x, const float* __restrict__ y,
    unsigned short* __restrict__ xb, unsigned short* __restrict__ yb)
{
    const int b   = blockIdx.x;
    const int row = b & (N_ROWS - 1);
    const bool isx = (b < N_ROWS);
    const float* in     = isx ? x  : y;
    unsigned short* out = isx ? xb : yb;
    const float post    = isx ? TEMP_INV : 1.0f;
    const int t = threadIdx.x;
    const float4* ip = (const float4*)(in + (size_t)row * D_K);
    float4 v = ip[t];
    float ss = v.x*v.x + v.y*v.y + v.z*v.z + v.w*v.w;
    #pragma unroll
    for (int off = 32; off > 0; off >>= 1)
        ss += __shfl_down(ss, off, 64);
    __shared__ float red[4];
    if ((t & 63) == 0) red[t >> 6] = ss;
    __syncthreads();
    float tot   = red[0] + red[1] + red[2] + red[3];
    float scale = post / fmaxf(sqrtf(tot), 1e-8f);
    us4_t o;
    o.x = f2bf(v.x * scale);
    o.y = f2bf(v.y * scale);
    o.z = f2bf(v.z * scale);
    o.w = f2bf(v.w * scale);
    *(us4_t*)(out + (size_t)row * D_K + t * 4) = o;
}

// ---------------- C = A . B^T  ----------------------------------------------------------
// 256x256 tile, BK=64, 512 threads = 8 waves (2 M-halves x 4 N-quarters), per-wave 128x64 C.
// R3 restructure: 3 phases / K-tile, ONE barrier per phase (was 4 phases x 2 barriers).
// Rationale (R2 post-mortem): tile time 6900 cyc vs m201's 3300 with identical per-tile
// work; the pre-MFMA barrier forced strict LDS<->MFMA alternation across waves. It is
// redundant here: per-wave lgkmcnt(0) orders own ds_reads before own MFMAs; stage->read
// visibility is published by vmcnt(N) + END-of-phase barrier; dbuf handles tile WAW.
// Removing it lets one wave's MFMA cluster overlap another wave's ds_read burst.
//
// STAGER == READER partition (per-wave in-order vmcnt = sufficient completion proof):
//   A rows [wm*128+qm*64, +64) staged by the 4 waves with that wm (2 loads/thread)
//   B rows [wn*64 +qn*32, +32) staged by the 2 waves with that wn (2 loads/thread)
// Stage issue order per tile: P1: A(q0),B(q0) [4]; P2: B(q1) [2]; P3: A(q1) [2].
//
// vmcnt ledger (steady state, max 8 outstanding/wave; oldest-first completion):
//   end P1: vmcnt(6) -> drains B(q1) of CURRENT tile (staged prev P2; read in P2)
//   end P2: vmcnt(6) -> drains A(q1) of CURRENT tile (staged prev P3; read in P3)
//   end P3: vmcnt(4) -> drains A(q0)+B(q0) of NEXT tile (staged this P1; read next P1/P3)
// Prologue: full tile-0 stage + vmcnt(0); tile-0 waits are no-ops by count.
// Epilogue tile (no stages): vmcnt(2) after P1, vmcnt(0) after P2.
//
// LDS swizzle: slot (row, g) holds global 8-elem k-group g ^ (row&7); applied on the
// GLOBAL source address during staging. Fragment read start group = (quad+4*kk)^(l15&7)
// -> measured ZERO SQ_LDS_BANK_CONFLICT (R1/R2). Keep 16x16x32 MFMA (32x32 regressed).
// Launch: PLAIN <<< >>> — cooperative launch was a ~24 us regression with no GEMM change (R2).
__global__ __launch_bounds__(512, 2) void cosim_gemm256_kernel(
    const unsigned short* __restrict__ Aus,
    const unsigned short* __restrict__ Bus,
    float* __restrict__ C)
{
    const __bf16* A = (const __bf16*)Aus;
    const __bf16* B = (const __bf16*)Bus;

    __shared__ __align__(16) __bf16 As[2][256 * 64];   // 64 KB
    __shared__ __align__(16) __bf16 Bs[2][256 * 64];   // 64 KB

    const int t    = threadIdx.x;
    const int lane = t & 63;
    const int wid  = t >> 6;       // 0..7
    const int wm   = wid >> 2;     // 0..1   M half
    const int wn   = wid & 3;      // 0..3   N quarter
    const int bm   = blockIdx.x;
    const int bn   = blockIdx.y;
    const int l15  = lane & 15;
    const int quad = lane >> 4;

    // ---- staging constants (see partition above) ----
    const int slA0 = wn * 64 + lane;          // 0..255  virtual lane over the wm-group
    const int slA1 = slA0 + 256;
    const int rA0 = slA0 >> 3, rA1 = slA1 >> 3;
    const int gA0 = (slA0 & 7) ^ (rA0 & 7);   // swizzled global k-group
    const int gA1 = (slA1 & 7) ^ (rA1 & 7);
    const size_t gaOff0 = (size_t)(bm * 256 + wm * 128 + rA0) * D_K + gA0 * 8;
    const size_t gaOff1 = (size_t)(bm * 256 + wm * 128 + rA1) * D_K + gA1 * 8;
    const int laOff0 = wm * 8192 + slA0 * 8;  // elems; + qm*4096
    const int laOff1 = wm * 8192 + slA1 * 8;
    const int slB0 = wm * 64 + lane;          // 0..127  virtual lane over the wn-group
    const int slB1 = slB0 + 128;
    const int rB0 = slB0 >> 3, rB1 = slB1 >> 3;
    const int gB0 = (slB0 & 7) ^ (rB0 & 7);
    const int gB1 = (slB1 & 7) ^ (rB1 & 7);
    const size_t gbOff0 = (size_t)(bn * 256 + wn * 64 + rB0) * D_K + gB0 * 8;
    const size_t gbOff1 = (size_t)(bn * 256 + wn * 64 + rB1) * D_K + gB1 * 8;
    const int lbOff0 = wn * 4096 + slB0 * 8;  // elems; + qn*2048
    const int lbOff1 = wn * 4096 + slB1 * 8;

#define STAGE_A(buf, qm, kelem) do { \
    gl_lds16(A + gaOff0 + (qm) * 65536 + (kelem), &As[buf][laOff0 + (qm) * 4096]); \
    gl_lds16(A + gaOff1 + (qm) * 65536 + (kelem), &As[buf][laOff1 + (qm) * 4096]); } while (0)
#define STAGE_B(buf, qn, kelem) do { \
    gl_lds16(B + gbOff0 + (qn) * 32768 + (kelem), &Bs[buf][lbOff0 + (qn) * 2048]); \
    gl_lds16(B + gbOff1 + (qn) * 32768 + (kelem), &Bs[buf][lbOff1 + (qn) * 2048]); } while (0)

    // ---- fragment read constants ----
    const int g0 = quad ^ (l15 & 7);          // kk=0 swizzled group
    const int g1 = (quad + 4) ^ (l15 & 7);    // kk=1
    const int aRd = (wm * 128 + l15) * 64;    // + qm*4096 + mi*1024 + g*8
    const int bRd = (wn * 64 + l15) * 64;     // + qn*2048 + ni*1024 + g*8

#define LDA(qm, mi, kk) (*(const bf8_t*)(&As[cur][aRd + (qm) * 4096 + (mi) * 1024 + ((kk) ? g1 : g0) * 8]))
#define LDB(qn, ni, kk) (*(const bf8_t*)(&Bs[cur][bRd + (qn) * 2048 + (ni) * 1024 + ((kk) ? g1 : g0) * 8]))

    f4_t acc[8][4];
    #pragma unroll
    for (int mi = 0; mi < 8; mi++)
        #pragma unroll
        for (int ni = 0; ni < 4; ni++) {
            acc[mi][ni][0] = 0.f; acc[mi][ni][1] = 0.f;
            acc[mi][ni][2] = 0.f; acc[mi][ni][3] = 0.f;
        }

    bf8_t af[4][2];   // A frags of current qm (4 mi x 2 kk)
    bf8_t bf[2][2];   // B frags of current qn (2 ni x 2 kk)

#define MFMA_QUAD(QM, QN) do { \
    __builtin_amdgcn_s_setprio(1); \
    _Pragma("unroll") \
    for (int mi = 0; mi < 4; mi++) \
        _Pragma("unroll") \
        for (int ni = 0; ni < 2; ni++) { \
            acc[(QM)*4+mi][(QN)*2+ni] = __builtin_amdgcn_mfma_f32_16x16x32_bf16( \
                af[mi][0], bf[ni][0], acc[(QM)*4+mi][(QN)*2+ni], 0, 0, 0); \
            acc[(QM)*4+mi][(QN)*2+ni] = __builtin_amdgcn_mfma_f32_16x16x32_bf16( \
                af[mi][1], bf[ni][1], acc[(QM)*4+mi][(QN)*2+ni], 0, 0, 0); \
        } \
    __builtin_amdgcn_s_setprio(0); } while (0)

#define FENCE_LGKM() do { \
    asm volatile("s_waitcnt lgkmcnt(0)"); \
    __builtin_amdgcn_sched_barrier(0); } while (0)

#define RD_AF(qm) do { _Pragma("unroll") \
    for (int mi = 0; mi < 4; mi++) { af[mi][0] = LDA(qm, mi, 0); af[mi][1] = LDA(qm, mi, 1); } } while (0)
#define RD_BF(qn) do { _Pragma("unroll") \
    for (int ni = 0; ni < 2; ni++) { bf[ni][0] = LDB(qn, ni, 0); bf[ni][1] = LDB(qn, ni, 1); } } while (0)

    // ---- prologue: full tile 0 into buf 0 ----
    STAGE_A(0, 0, 0); STAGE_B(0, 0, 0);
    STAGE_B(0, 1, 0); STAGE_A(0, 1, 0);
    asm volatile("s_waitcnt vmcnt(0)");
    __builtin_amdgcn_s_barrier();

    // ---- main loop: compute tile tt from buf cur, stage tile tt+1 into nxt ----
    for (int tt = 0; tt < 15; ++tt) {
        const int cur = tt & 1;
        const int nxt = cur ^ 1;
        const int k1  = (tt + 1) * 64;

        // P1: quadrant (0,0); stage A(q0)+B(q0) of next tile
        RD_AF(0); RD_BF(0);
        STAGE_A(nxt, 0, k1); STAGE_B(nxt, 0, k1);
        FENCE_LGKM();
        MFMA_QUAD(0, 0);
        asm volatile("s_waitcnt vmcnt(6)");   // B(q1) of current tile now resident
        __builtin_amdgcn_s_barrier();

        // P2: quadrant (0,1) — reuse af; stage B(q1) of next tile
        RD_BF(1);
        STAGE_B(nxt, 1, k1);
        FENCE_LGKM();
        MFMA_QUAD(0, 1);
        asm volatile("s_waitcnt vmcnt(6)");   // A(q1) of current tile now resident
        __builtin_amdgcn_s_barrier();

        // P3: quadrants (1,1) then (1,0) — read A(q1), reuse bf; then re-read B(q0)
        RD_AF(1);
        STAGE_A(nxt, 1, k1);
        FENCE_LGKM();
        MFMA_QUAD(1, 1);
        RD_BF(0);
        FENCE_LGKM();
        MFMA_QUAD(1, 0);
        asm volatile("s_waitcnt vmcnt(4)");   // A(q0)+B(q0) of next tile now resident
        __builtin_amdgcn_s_barrier();
    }

    // ---- epilogue: tile 15 in buf 1; in-flight on entry: B(q1) (oldest 2), A(q1) ----
    {
        const int cur = 1;
        // P1
        RD_AF(0); RD_BF(0);
        FENCE_LGKM();
        MFMA_QUAD(0, 0);
        asm volatile("s_waitcnt vmcnt(2)");   // drains B(q1) of tile 15
        __builtin_amdgcn_s_barrier();
        // P2
        RD_BF(1);
        FENCE_LGKM();
        MFMA_QUAD(0, 1);
        asm volatile("s_waitcnt vmcnt(0)");   // drains A(q1) of tile 15
        __builtin_amdgcn_s_barrier();
        // P3
        RD_AF(1);
        FENCE_LGKM();
        MFMA_QUAD(1, 1);
        RD_BF(0);
        FENCE_LGKM();
        MFMA_QUAD(1, 0);
    }

    // ---- C write: C/D layout col = lane&15, row = (lane>>4)*4 + reg [m89/m91 verified] ----
    #pragma unroll
    for (int mi = 0; mi < 8; mi++) {
        const int row = bm * 256 + wm * 128 + mi * 16 + quad * 4;
        #pragma unroll
        for (int ni = 0; ni < 4; ni++) {
            const int col = bn * 256 + wn * 64 + ni * 16 + l15;
            #pragma unroll
            for (int r = 0; r < 4; r++)
                C[(size_t)(row + r) * N_ROWS + col] = acc[mi][ni][r];
        }
    }

#undef STAGE_A
#undef STAGE_B
#undef LDA
#undef LDB
#undef MFMA_QUAD
#undef FENCE_LGKM
#undef RD_AF
#undef RD_BF
}

extern "C" void kernel_launch(void* const* d_in, const int* in_sizes, int n_in,
                              void* d_out, int out_size, void* d_ws, size_t ws_size,
                              hipStream_t stream)
{
    const float* x = (const float*)d_in[0];
    const float* y = (const float*)d_in[1];
    float* out = (float*)d_out;

    unsigned short* xb = (unsigned short*)d_ws;                 // 8 MB
    unsigned short* yb = xb + (size_t)N_ROWS * D_K;             // 8 MB

    norm_rows_kernel<<<2 * N_ROWS, 256, 0, stream>>>(x, y, xb, yb);

    dim3 grid(N_ROWS / 256, N_ROWS / 256);                      // 16x16 = 256 blocks, 1/CU
    cosim_gemm256_kernel<<<grid, 512, 0, stream>>>(xb, yb, out);
}